// Round 2
// baseline (145.343 us; speedup 1.0000x reference)
//
#include <hip/hip_runtime.h>
#include <hip/hip_bf16.h>

#define B_   64
#define L_   2048
#define DTS  8
#define DSEQ 120
#define DIN  128
#define H_   64
#define TILE 64
#define NT   (L_ / TILE)   // 32 tiles per batch row

typedef unsigned short u16;
typedef __bf16 bf16x8 __attribute__((ext_vector_type(8)));
typedef float  f32x4  __attribute__((ext_vector_type(4)));

// RReLU eval slope = (1/8 + 1/3)/2 = 11/48
__device__ __forceinline__ float rrelu_f(float x) {
    return x >= 0.f ? x : x * 0.22916666666666666f;
}

// f32 -> bf16 bits, round-to-nearest-even (inputs are finite)
__device__ __forceinline__ u16 f2bf(float x) {
    unsigned u = __float_as_uint(x);
    return (u16)((u + 0x7FFFu + ((u >> 16) & 1u)) >> 16);
}
__device__ __forceinline__ float bf2f(u16 u) {
    return __uint_as_float(((unsigned)u) << 16);
}

// ---------------- kernel 0: pack Wk/Wv into hi/lo bf16 in B-fragment order ----------------
// packed[((ni*4+kk)*64 + lane)*8 + j] = W[(kk*32 + (lane>>4)*8 + j)*64 + (ni*16 + (lane&15))]
// so the tile kernel's wave reads one coalesced bf16x8 per (ni,kk) per lane.
__global__ void prep_kernel(const float* __restrict__ Wk, const float* __restrict__ Wv,
                            u16* __restrict__ pkh, u16* __restrict__ pkl,
                            u16* __restrict__ pvh, u16* __restrict__ pvl)
{
    const int f = blockIdx.x * 256 + threadIdx.x;     // 64 blocks -> 16384 = 2*8192
    const int idx = f & 8191;
    const bool isK = f < 8192;
    const float* W = isK ? Wk : Wv;
    u16* hi = isK ? pkh : pvh;
    u16* lo = isK ? pkl : pvl;
    const int j = idx & 7, lane = (idx >> 3) & 63, kk = (idx >> 9) & 3, ni = idx >> 11;
    const int kd = kk * 32 + (lane >> 4) * 8 + j;
    const int n  = ni * 16 + (lane & 15);
    const float v = W[kd * H_ + n];
    const u16 h = f2bf(v);
    hi[idx] = h;
    lo[idx] = f2bf(v - bf2f(h));
}

// ---------------- kernel 1: q_last[b][h] in full f32 ----------------
__global__ void qlast_kernel(const float* __restrict__ ts, const float* __restrict__ seq,
                             const int* __restrict__ lengths,
                             const float* __restrict__ Wq, const float* __restrict__ bq,
                             float* __restrict__ qlast)
{
    const int b = blockIdx.x, h = threadIdx.x;        // 64 blocks x 64 threads
    const int l = lengths[b] - 1;
    const float* tsr = ts  + ((size_t)b * L_ + l) * DTS;
    const float* sqr = seq + ((size_t)b * L_ + l) * DSEQ;
    float acc = bq[h];
    #pragma unroll
    for (int d = 0; d < DTS; ++d)  acc += tsr[d] * Wq[d * H_ + h];
    for (int d = 0; d < DSEQ; ++d) acc += sqr[d] * Wq[(DTS + d) * H_ + h];
    qlast[b * H_ + h] = rrelu_f(acc);
}

// ---------------- kernel 2: per-(b,tile) K/V via split-bf16 MFMA + softmax partial ----------------
__global__ __launch_bounds__(256) void tile_kernel(
    const float* __restrict__ ts, const float* __restrict__ seq,
    const int* __restrict__ lengths,
    const u16* __restrict__ pkh, const u16* __restrict__ pkl,
    const u16* __restrict__ pvh, const u16* __restrict__ pvl,
    const float* __restrict__ bk, const float* __restrict__ bv,
    const float* __restrict__ qlast,
    float* __restrict__ pm, float* __restrict__ pd, float* __restrict__ pacc)
{
    const int b = blockIdx.y, t = blockIdx.x;
    const int tid = threadIdx.x;
    const int len = lengths[b];
    const int ls = t * TILE;
    const int pbase = b * NT + t;

    if (ls >= len) {  // fully masked tile: write empty partial (ws is poisoned!)
        if (tid < H_) pacc[(size_t)pbase * H_ + tid] = 0.f;
        if (tid == 0) { pm[pbase] = -INFINITY; pd[pbase] = 0.f; }
        return;
    }
    const int nv = min(TILE, len - ls);

    __shared__ __align__(16) u16 xh[TILE][136];   // bf16 hi of x tile (+8 pad)
    __shared__ __align__(16) u16 xl[TILE][136];   // bf16 lo
    __shared__ float k_s[TILE][65];               // +1 pad: conflict-free column reads
    __shared__ float v_s[TILE][65];
    __shared__ float qls[H_];
    __shared__ float sc[TILE];
    __shared__ float red[4][H_];

    // ---- stage x tile (f32 -> hi/lo bf16): 64 rows x 32 float4 chunks ----
    for (int c = tid; c < TILE * 32; c += 256) {
        const int row = c >> 5, ch = c & 31;      // ch 0..1 = ts, 2..31 = seq
        const float* src = (ch < 2)
            ? ts  + ((size_t)b * L_ + ls + row) * DTS  + ch * 4
            : seq + ((size_t)b * L_ + ls + row) * DSEQ + (ch - 2) * 4;
        const float4 v = *(const float4*)src;
        const u16 h0 = f2bf(v.x), h1 = f2bf(v.y), h2 = f2bf(v.z), h3 = f2bf(v.w);
        const u16 g0 = f2bf(v.x - bf2f(h0)), g1 = f2bf(v.y - bf2f(h1));
        const u16 g2 = f2bf(v.z - bf2f(h2)), g3 = f2bf(v.w - bf2f(h3));
        unsigned* ph = (unsigned*)&xh[row][ch * 4];
        unsigned* pl = (unsigned*)&xl[row][ch * 4];
        ph[0] = (unsigned)h0 | ((unsigned)h1 << 16);
        ph[1] = (unsigned)h2 | ((unsigned)h3 << 16);
        pl[0] = (unsigned)g0 | ((unsigned)g1 << 16);
        pl[1] = (unsigned)g2 | ((unsigned)g3 << 16);
    }
    if (tid < H_) qls[tid] = qlast[b * H_ + tid];
    __syncthreads();

    const int wave = tid >> 6, lane = tid & 63;
    const int quad = lane >> 4, l16 = lane & 15;
    const int m0 = wave * 16;   // each wave owns 16 rows (l) of the tile

    // A fragments: A[m=lane&15][k=quad*8+j], 16B ds_read_b128 per frag
    const u16* hrow = &xh[m0 + l16][0];
    const u16* lrow = &xl[m0 + l16][0];
    bf16x8 ah[4], al[4];
    #pragma unroll
    for (int kk = 0; kk < 4; ++kk) {
        ah[kk] = *(const bf16x8*)(hrow + kk * 32 + quad * 8);
        al[kk] = *(const bf16x8*)(lrow + kk * 32 + quad * 8);
    }

    #pragma unroll
    for (int ni = 0; ni < 4; ++ni) {
        const int n = ni * 16 + l16;
        f32x4 ak = {0.f, 0.f, 0.f, 0.f};
        f32x4 av = {0.f, 0.f, 0.f, 0.f};
        #pragma unroll
        for (int kk = 0; kk < 4; ++kk) {
            const size_t off = (size_t)(((ni * 4 + kk) * 64 + lane)) * 8;
            const bf16x8 bkh = *(const bf16x8*)(pkh + off);
            const bf16x8 bkl = *(const bf16x8*)(pkl + off);
            const bf16x8 bvh = *(const bf16x8*)(pvh + off);
            const bf16x8 bvl = *(const bf16x8*)(pvl + off);
            // split-bf16: hi*hi + lo*hi + hi*lo  (~2^-16 relative error)
            ak = __builtin_amdgcn_mfma_f32_16x16x32_bf16(ah[kk], bkh, ak, 0, 0, 0);
            ak = __builtin_amdgcn_mfma_f32_16x16x32_bf16(al[kk], bkh, ak, 0, 0, 0);
            ak = __builtin_amdgcn_mfma_f32_16x16x32_bf16(ah[kk], bkl, ak, 0, 0, 0);
            av = __builtin_amdgcn_mfma_f32_16x16x32_bf16(ah[kk], bvh, av, 0, 0, 0);
            av = __builtin_amdgcn_mfma_f32_16x16x32_bf16(al[kk], bvh, av, 0, 0, 0);
            av = __builtin_amdgcn_mfma_f32_16x16x32_bf16(ah[kk], bvl, av, 0, 0, 0);
        }
        // epilogue: bias + rrelu; C/D map (m89-verified): col = lane&15, row = quad*4 + r
        const float bbk = bk[n], bbv = bv[n];
        #pragma unroll
        for (int r = 0; r < 4; ++r) {
            const int row = m0 + quad * 4 + r;
            k_s[row][n] = rrelu_f(ak[r] + bbk);
            v_s[row][n] = rrelu_f(av[r] + bbv);
        }
    }
    __syncthreads();

    // ---- scores + tile-local softmax stats (wave 0, one lane per l) ----
    if (wave == 0) {
        const int l = lane;
        float s = 0.f;
        #pragma unroll 8
        for (int h = 0; h < H_; ++h) s += qls[h] * k_s[l][h];   // banks (l+h)%32: free
        if (l >= nv) s = -INFINITY;
        float m = s;
        #pragma unroll
        for (int off = 32; off; off >>= 1) m = fmaxf(m, __shfl_xor(m, off));
        const float p = __expf(s - m);    // exp(-inf)=0 for masked l
        float d = p;
        #pragma unroll
        for (int off = 32; off; off >>= 1) d += __shfl_xor(d, off);
        sc[l] = p;
        if (lane == 0) { pm[pbase] = m; pd[pbase] = d; }
    }
    __syncthreads();

    // ---- weighted V partial: lane = h, each wave covers 16 rows ----
    {
        const int h = lane;
        float acc = 0.f;
        #pragma unroll
        for (int i = 0; i < 16; ++i)
            acc += sc[wave * 16 + i] * v_s[wave * 16 + i][h];
        red[wave][h] = acc;
    }
    __syncthreads();
    if (tid < H_)
        pacc[(size_t)pbase * H_ + tid] = red[0][tid] + red[1][tid] + red[2][tid] + red[3][tid];
}

// ---------------- kernel 3: combine 32 tile partials per batch ----------------
__global__ void combine_kernel(const float* __restrict__ pm, const float* __restrict__ pd,
                               const float* __restrict__ pacc, float* __restrict__ out)
{
    const int b = blockIdx.x, h = threadIdx.x;   // 64 blocks x 64 threads
    float m = -INFINITY;
    for (int t = 0; t < NT; ++t) m = fmaxf(m, pm[b * NT + t]);
    float den = 0.f, num = 0.f;
    for (int t = 0; t < NT; ++t) {
        const float w = __expf(pm[b * NT + t] - m);   // 0 for empty tiles
        den += pd[b * NT + t] * w;
        num += pacc[(size_t)(b * NT + t) * H_ + h] * w;
    }
    out[b * H_ + h] = num / den;
}

extern "C" void kernel_launch(void* const* d_in, const int* in_sizes, int n_in,
                              void* d_out, int out_size, void* d_ws, size_t ws_size,
                              hipStream_t stream)
{
    const float* ts      = (const float*)d_in[0];
    const float* seq     = (const float*)d_in[1];
    const int*   lengths = (const int*)d_in[2];
    const float* Wk      = (const float*)d_in[3];
    const float* bk      = (const float*)d_in[4];
    const float* Wq      = (const float*)d_in[5];
    const float* bq      = (const float*)d_in[6];
    const float* Wv      = (const float*)d_in[7];
    const float* bv      = (const float*)d_in[8];

    float* ws    = (float*)d_ws;
    float* qlast = ws;                    // 64*64      = 4096 f32
    float* pm    = ws + 4096;             // 64*32      = 2048
    float* pd    = ws + 6144;             // 64*32      = 2048
    float* pacc  = ws + 8192;             // 64*32*64   = 131072
    u16*  packw  = (u16*)(ws + 139264);   // 4 x 8192 u16 = 64 KB
    u16* pkh = packw;
    u16* pkl = packw + 8192;
    u16* pvh = packw + 16384;
    u16* pvl = packw + 24576;

    prep_kernel<<<dim3(64), dim3(256), 0, stream>>>(Wk, Wv, pkh, pkl, pvh, pvl);
    qlast_kernel<<<dim3(B_), dim3(H_), 0, stream>>>(ts, seq, lengths, Wq, bq, qlast);
    tile_kernel<<<dim3(NT, B_), dim3(256), 0, stream>>>(ts, seq, lengths,
                                                        pkh, pkl, pvh, pvl, bk, bv,
                                                        qlast, pm, pd, pacc);
    combine_kernel<<<dim3(B_), dim3(H_), 0, stream>>>(pm, pd, pacc, (float*)d_out);
}